// Round 7
// baseline (97.215 us; speedup 1.0000x reference)
//
#include <hip/hip_runtime.h>
#include <math.h>

#define NN 100000
#define EE 1600000
#define HH 128
#define RR 500
#define AA 16
#define LN_EPS 1e-5f

// Bucketing: nodes -> 391 buckets of 256; payload packs (src<<8 | dst&255) in u32.
#define BSH 8
#define NPB 256
#define NB 391                   // ceil(100000/256)
#define MAXPB 4608               // mean 4096, sigma 64 -> +8 sigma
#define EPW 8192                 // edges per scatter workgroup
#define SCT 512                  // scatter threads
#define NWG_SC ((EE + EPW - 1) / EPW)   // 196

__global__ void k_init(unsigned int* __restrict__ p, int n) {
    int i = threadIdx.x;
    for (int j = i; j < n; j += blockDim.x) p[j] = 0u;
}

// ---------------- bucket path ----------------

// Bucket edges by dst: LDS bucket histogram -> one reserve atomic per (WG,bucket)
// -> per-edge LDS rank atomic + direct global payload write.
__global__ __launch_bounds__(SCT) void k_scatter(const int* __restrict__ src,
                                                 const int* __restrict__ dst,
                                                 unsigned int* __restrict__ gctr,
                                                 unsigned int* __restrict__ payload) {
    __shared__ unsigned int hist[512], rank[512], hbase[512];
    const int t = threadIdx.x;
    hist[t] = 0u; rank[t] = 0u; hbase[t] = 0u;
    __syncthreads();
    const int e0 = blockIdx.x * EPW;
    const int ecnt = min(EPW, EE - e0);
    const int nv = ecnt >> 2;
    const int4* d4 = reinterpret_cast<const int4*>(dst + e0);
    const int4* s4 = reinterpret_cast<const int4*>(src + e0);

    // pass A: bucket histogram (vectorized)
    for (int k = t; k < nv; k += SCT) {
        int4 d = d4[k];
        atomicAdd(&hist[((unsigned)d.x) >> BSH], 1u);
        atomicAdd(&hist[((unsigned)d.y) >> BSH], 1u);
        atomicAdd(&hist[((unsigned)d.z) >> BSH], 1u);
        atomicAdd(&hist[((unsigned)d.w) >> BSH], 1u);
    }
    __syncthreads();

    // reserve global space: one atomic per (WG,bucket)
    if (t < NB && hist[t] > 0u) hbase[t] = atomicAdd(&gctr[t], hist[t]);
    __syncthreads();

    // pass B: rank within (WG,bucket), direct global write
    for (int k = t; k < nv; k += SCT) {
        int4 d = d4[k];
        int4 s = s4[k];
        #define EMIT(SS, DD) { \
            unsigned int dd = (unsigned)(DD), ss = (unsigned)(SS); \
            unsigned int b = dd >> BSH; \
            unsigned int r = atomicAdd(&rank[b], 1u); \
            unsigned int slot = hbase[b] + r; \
            if (slot < MAXPB) payload[(size_t)b * MAXPB + slot] = (ss << BSH) | (dd & (NPB - 1)); }
        EMIT(s.x, d.x) EMIT(s.y, d.y) EMIT(s.z, d.z) EMIT(s.w, d.w)
        #undef EMIT
    }
}

// Per bucket, 1024 threads: LDS degree histogram; write rsv = rsqrt(deg), g = rsv*f.
__global__ __launch_bounds__(1024) void k_bdeg_g(const unsigned int* __restrict__ gctr,
                                                 const unsigned int* __restrict__ payload,
                                                 const float* __restrict__ nf,
                                                 float* __restrict__ rsv, float* __restrict__ g) {
    __shared__ unsigned int hist[NPB];
    const int b = blockIdx.x, t = threadIdx.x;
    if (t < NPB) hist[t] = 0u;
    __syncthreads();
    const unsigned int cnt = min(gctr[b], (unsigned int)MAXPB);
    const unsigned int* pl = payload + (size_t)b * MAXPB;
    const uint4* pl4 = reinterpret_cast<const uint4*>(pl);
    const unsigned int nv = cnt >> 2;
    for (unsigned int k = t; k < nv; k += 1024) {
        uint4 p = pl4[k];
        atomicAdd(&hist[p.x & (NPB - 1)], 1u);
        atomicAdd(&hist[p.y & (NPB - 1)], 1u);
        atomicAdd(&hist[p.z & (NPB - 1)], 1u);
        atomicAdd(&hist[p.w & (NPB - 1)], 1u);
    }
    for (unsigned int k = (nv << 2) + t; k < cnt; k += 1024)
        atomicAdd(&hist[pl[k] & (NPB - 1)], 1u);
    __syncthreads();
    if (t < NPB) {
        int node = (b << BSH) + t;
        if (node < NN) {
            float df = 1.0f + (float)hist[t];
            float rs = rsqrtf(df);
            rsv[node] = rs;
            float2 f = *reinterpret_cast<const float2*>(&nf[2 * node]);
            float2 gv; gv.x = rs * f.x; gv.y = rs * f.y;
            *reinterpret_cast<float2*>(&g[2 * node]) = gv;
        }
    }
}

// Per bucket, 1024 threads: aggregate g[src] into x/y LDS planes, fold self-loop,
// then GCN channel pass + relu; write per-bucket partials Sp[b][128], T2p[b].
__global__ __launch_bounds__(1024) void k_bagg_node(const unsigned int* __restrict__ gctr,
        const unsigned int* __restrict__ payload,
        const float* __restrict__ g, const float* __restrict__ rsv,
        const float* __restrict__ gcn_w, const float* __restrict__ gcn_b,
        float* __restrict__ Sp, float* __restrict__ T2p) {
    __shared__ float agg[NPB * 2];      // plane 0: x, plane 1: y
    __shared__ float shSf[HH];
    __shared__ float shw[16];
    const int b = blockIdx.x, t = threadIdx.x;
    if (t < NPB * 2) agg[t] = 0.f;
    if (t < HH) shSf[t] = 0.f;
    __syncthreads();
    const unsigned int cnt = min(gctr[b], (unsigned int)MAXPB);
    const unsigned int* pl = payload + (size_t)b * MAXPB;
    const uint4* pl4 = reinterpret_cast<const uint4*>(pl);
    const unsigned int nv = cnt >> 2;
    for (unsigned int k = t; k < nv; k += 1024) {
        uint4 p = pl4[k];
        #define ACC(P) { \
            unsigned int s = (P) >> BSH, dl = (P) & (NPB - 1); \
            float2 gv = *reinterpret_cast<const float2*>(&g[2 * s]); \
            atomicAdd(&agg[dl],       gv.x); \
            atomicAdd(&agg[NPB + dl], gv.y); }
        ACC(p.x) ACC(p.y) ACC(p.z) ACC(p.w)
        #undef ACC
    }
    for (unsigned int k = (nv << 2) + t; k < cnt; k += 1024) {
        unsigned int p = pl[k];
        unsigned int s = p >> BSH, dl = p & (NPB - 1);
        float2 gv = *reinterpret_cast<const float2*>(&g[2 * s]);
        atomicAdd(&agg[dl],       gv.x);
        atomicAdd(&agg[NPB + dl], gv.y);
    }
    __syncthreads();

    const int nvalid = min(NPB, NN - (b << BSH));
    if (t < nvalid) {
        int node = (b << BSH) + t;
        float rs = rsv[node];
        float2 gv = *reinterpret_cast<const float2*>(&g[2 * node]);
        agg[t]       = rs * (agg[t]       + gv.x);
        agg[NPB + t] = rs * (agg[NPB + t] + gv.y);
    }
    __syncthreads();

    // channel pass: ch = t&127, 8 node slots (slot = t>>7)
    const int ch = t & (HH - 1), slot = t >> 7;
    const float w0 = gcn_w[ch], w1 = gcn_w[HH + ch], bb = gcn_b[ch];
    float accS = 0.f, accT2 = 0.f;
    for (int j = slot; j < nvalid; j += 8) {
        float x = fmaf(agg[j], w0, fmaf(agg[NPB + j], w1, bb));
        float r = fmaxf(x, 0.f);
        accS  += r;
        accT2 += r * r;
    }
    atomicAdd(&shSf[ch], accS);          // LDS float atomic, 8-way same-address
    float v = accT2;
    for (int o = 32; o; o >>= 1) v += __shfl_down(v, o, 64);
    if ((t & 63) == 0) shw[t >> 6] = v;
    __syncthreads();
    if (t < HH) Sp[(size_t)b * HH + t] = shSf[t];     // non-atomic partial store
    if (t == 0) {
        float s2 = 0.f;
        #pragma unroll
        for (int w = 0; w < 16; ++w) s2 += shw[w];
        T2p[b] = s2;
    }
}

// Single block, 1024 threads: sum partials, LN-collapse, fc1 (8-way k-split),
// fc2, log_softmax.
__global__ __launch_bounds__(1024) void k_final_b(const float* __restrict__ Sp,
                        const float* __restrict__ T2p,
                        const float* __restrict__ esn,
                        const float* __restrict__ ln_w, const float* __restrict__ ln_b,
                        const float* __restrict__ fc1_w, const float* __restrict__ fc1_b,
                        const float* __restrict__ fc2_w, const float* __restrict__ fc2_b,
                        float* __restrict__ out) {
    const int t = threadIdx.x;
    const int ch = t & (HH - 1), sl = t >> 7;        // sl in 0..7
    __shared__ float psum[8][HH];
    __shared__ float sh_pooled[HH], sh_z[HH], sh_logits[AA];
    __shared__ float shw[16], shred[2], sh_t2[1];

    // S partial sum over buckets (coalesced: consecutive ch -> consecutive addr)
    float sacc = 0.f;
    for (int b = sl; b < NB; b += 8) sacc += Sp[(size_t)b * HH + ch];
    psum[sl][ch] = sacc;

    // T2 sum over buckets
    float v = (t < NB) ? T2p[t] : 0.f;
    for (int o = 32; o; o >>= 1) v += __shfl_down(v, o, 64);
    if ((t & 63) == 0) shw[t >> 6] = v;
    __syncthreads();

    if (t < HH) {
        float s = 0.f;
        #pragma unroll
        for (int k = 0; k < 8; ++k) s += psum[k][t];
        sh_pooled[t] = s;                             // S_ch for now
        float vv = s;
        for (int o = 32; o; o >>= 1) vv += __shfl_down(vv, o, 64);
        if ((t & 63) == 0) shred[t >> 6] = vv;
    }
    if (t == 0) {
        float s2 = 0.f;
        #pragma unroll
        for (int w = 0; w < 16; ++w) s2 += shw[w];
        sh_t2[0] = s2;
    }
    __syncthreads();

    const float T1 = shred[0] + shred[1];
    const float T2 = sh_t2[0];
    const float cnt = (float)NN * (float)HH;
    const float mean = T1 / cnt;
    const float var  = T2 / cnt - mean * mean;
    const float denom = sqrtf(var) + LN_EPS;
    if (t < HH)
        sh_pooled[t] = ln_w[t] * (sh_pooled[t] - (float)NN * mean) / denom + (float)NN * ln_b[t];
    __syncthreads();

    // fc1: k-split 8 ways
    float acc = 0.f;
    for (int k = sl; k < HH + RR; k += 8) {
        float zin = (k < HH) ? sh_pooled[k] : esn[k - HH];
        acc = fmaf(zin, fc1_w[(size_t)k * HH + ch], acc);
    }
    psum[sl][ch] = acc;
    __syncthreads();
    if (t < HH) {
        float a = fc1_b[t];
        #pragma unroll
        for (int k = 0; k < 8; ++k) a += psum[k][t];
        sh_z[t] = fmaxf(a, 0.f);
    }
    __syncthreads();

    if (t < AA) {
        float l = fc2_b[t];
        for (int j = 0; j < HH; ++j)
            l = fmaf(sh_z[j], fc2_w[j * AA + t], l);
        sh_logits[t] = l;
    }
    __syncthreads();

    if (t == 0) {
        float m = sh_logits[0];
        for (int a = 1; a < AA; ++a) m = fmaxf(m, sh_logits[a]);
        float sum = 0.f;
        for (int a = 0; a < AA; ++a) sum += expf(sh_logits[a] - m);
        float lse = m + logf(sum);
        for (int a = 0; a < AA; ++a) out[a] = sh_logits[a] - lse;
    }
}

// ---------------- fallback path (round-2 known-good) ----------------

__global__ void k_deg1(const int* __restrict__ dst, int* __restrict__ deg, int e) {
    int i = blockIdx.x * blockDim.x + threadIdx.x;
    if (i < e) atomicAdd(&deg[dst[i]], 1);
}

__global__ void k_g1(const int* __restrict__ deg, const float* __restrict__ nf,
                     float* __restrict__ degf, float* __restrict__ g, int n) {
    int i = blockIdx.x * blockDim.x + threadIdx.x;
    if (i < n) {
        float df = (float)(1 + deg[i]);
        degf[i] = df;
        float rs = rsqrtf(df);
        float2 f = *reinterpret_cast<const float2*>(&nf[2 * i]);
        float2 gv; gv.x = rs * f.x; gv.y = rs * f.y;
        *reinterpret_cast<float2*>(&g[2 * i]) = gv;
    }
}

__global__ void k_edge1(const int* __restrict__ src, const int* __restrict__ dst,
                        const float* __restrict__ g, float* __restrict__ B, int e) {
    int i = blockIdx.x * blockDim.x + threadIdx.x;
    if (i < e) {
        int s = src[i], d = dst[i];
        float2 gv = *reinterpret_cast<const float2*>(&g[2 * s]);
        atomicAdd(&B[2 * d],     gv.x);
        atomicAdd(&B[2 * d + 1], gv.y);
    }
}

__global__ void k_node(const float* __restrict__ nf, const float* __restrict__ degf,
                       const float* __restrict__ B,
                       const float* __restrict__ gcn_w, const float* __restrict__ gcn_b,
                       float* __restrict__ S, float* __restrict__ T2, int n) {
    const int ch   = threadIdx.x & (HH - 1);
    const int slot = threadIdx.x >> 7;
    const float w0 = gcn_w[ch];
    const float w1 = gcn_w[HH + ch];
    const float b  = gcn_b[ch];
    float accS = 0.f, accT2 = 0.f;
    for (int i = blockIdx.x * 2 + slot; i < n; i += gridDim.x * 2) {
        float df   = degf[i];
        float invd = 1.0f / df;
        float rs   = rsqrtf(df);
        float2 bv = *reinterpret_cast<const float2*>(&B[2 * i]);
        float2 f  = *reinterpret_cast<const float2*>(&nf[2 * i]);
        float b0 = rs * bv.x + f.x * invd;
        float b1 = rs * bv.y + f.y * invd;
        float xv = fmaf(b0, w0, fmaf(b1, w1, b));
        float r  = fmaxf(xv, 0.f);
        accS  += r;
        accT2 += r * r;
    }
    __shared__ float shS[HH];
    if (slot == 1) shS[ch] = accS;
    __syncthreads();
    if (slot == 0) atomicAdd(&S[ch], accS + shS[ch]);
    float v = accT2;
    for (int o = 32; o; o >>= 1) v += __shfl_down(v, o, 64);
    __shared__ float shw[4];
    if ((threadIdx.x & 63) == 0) shw[threadIdx.x >> 6] = v;
    __syncthreads();
    if (threadIdx.x == 0) atomicAdd(T2, shw[0] + shw[1] + shw[2] + shw[3]);
}

__global__ void k_final(const float* __restrict__ S, const float* __restrict__ T2ptr,
                        const float* __restrict__ esn,
                        const float* __restrict__ ln_w, const float* __restrict__ ln_b,
                        const float* __restrict__ fc1_w, const float* __restrict__ fc1_b,
                        const float* __restrict__ fc2_w, const float* __restrict__ fc2_b,
                        float* __restrict__ out) {
    const int t = threadIdx.x;
    __shared__ float sh_pooled[HH];
    __shared__ float sh_z[HH];
    __shared__ float sh_logits[AA];
    __shared__ float shred[2];

    float s = S[t];
    float v = s;
    for (int o = 32; o; o >>= 1) v += __shfl_down(v, o, 64);
    if ((t & 63) == 0) shred[t >> 6] = v;
    __syncthreads();
    const float T1 = shred[0] + shred[1];
    const float T2 = *T2ptr;
    const float cnt = (float)NN * (float)HH;
    const float mean = T1 / cnt;
    const float var  = T2 / cnt - mean * mean;
    const float denom = sqrtf(var) + LN_EPS;
    sh_pooled[t] = ln_w[t] * (s - (float)NN * mean) / denom + (float)NN * ln_b[t];
    __syncthreads();

    float acc = fc1_b[t];
    for (int k = 0; k < HH; ++k)
        acc = fmaf(sh_pooled[k], fc1_w[k * HH + t], acc);
    for (int k = 0; k < RR; ++k)
        acc = fmaf(esn[k], fc1_w[(HH + k) * HH + t], acc);
    sh_z[t] = fmaxf(acc, 0.f);
    __syncthreads();

    if (t < AA) {
        float l = fc2_b[t];
        for (int j = 0; j < HH; ++j)
            l = fmaf(sh_z[j], fc2_w[j * AA + t], l);
        sh_logits[t] = l;
    }
    __syncthreads();

    if (t == 0) {
        float m = sh_logits[0];
        for (int a = 1; a < AA; ++a) m = fmaxf(m, sh_logits[a]);
        float sum = 0.f;
        for (int a = 0; a < AA; ++a) sum += expf(sh_logits[a] - m);
        float lse = m + logf(sum);
        for (int a = 0; a < AA; ++a) out[a] = sh_logits[a] - lse;
    }
}

extern "C" void kernel_launch(void* const* d_in, const int* in_sizes, int n_in,
                              void* d_out, int out_size, void* d_ws, size_t ws_size,
                              hipStream_t stream) {
    const float* nf     = (const float*)d_in[0];
    const int*   ei     = (const int*)d_in[1];
    const float* esn    = (const float*)d_in[2];
    const float* gcn_w  = (const float*)d_in[3];
    const float* gcn_b  = (const float*)d_in[4];
    const float* ln_w   = (const float*)d_in[5];
    const float* ln_b   = (const float*)d_in[6];
    const float* fc1_w  = (const float*)d_in[7];
    const float* fc1_b  = (const float*)d_in[8];
    const float* fc2_w  = (const float*)d_in[9];
    const float* fc2_b  = (const float*)d_in[10];
    float* out = (float*)d_out;
    float* ws  = (float*)d_ws;

    // Bucket-path layout (word offsets):
    //   gctr:0(512) | Sp:512(NB*HH) | T2p(NB) | payload(NB*MAXPB) | rsv(NN) | g(2NN)
    const size_t OFF_SP      = 512;
    const size_t OFF_T2P     = OFF_SP + (size_t)NB * HH;            // 50560
    const size_t OFF_PAYLOAD = (OFF_T2P + NB + 3) & ~(size_t)3;     // 50952, 16B-aligned
    const size_t OFF_RSV     = OFF_PAYLOAD + (size_t)NB * MAXPB;
    const size_t OFF_G       = OFF_RSV + NN;                        // even -> float2 ok
    const size_t NEED_BKT    = (OFF_G + 2 * (size_t)NN) * 4;

    if (ws_size >= NEED_BKT) {
        unsigned int* gctr    = (unsigned int*)ws;
        float*        Sp      = ws + OFF_SP;
        float*        T2p     = ws + OFF_T2P;
        unsigned int* payload = (unsigned int*)ws + OFF_PAYLOAD;
        float*        rsv     = ws + OFF_RSV;
        float*        g       = ws + OFF_G;

        hipLaunchKernelGGL(k_init,      dim3(1),      dim3(512),  0, stream, (unsigned int*)ws, 512);
        hipLaunchKernelGGL(k_scatter,   dim3(NWG_SC), dim3(SCT),  0, stream, ei, ei + EE, gctr, payload);
        hipLaunchKernelGGL(k_bdeg_g,    dim3(NB),     dim3(1024), 0, stream, gctr, payload, nf, rsv, g);
        hipLaunchKernelGGL(k_bagg_node, dim3(NB),     dim3(1024), 0, stream, gctr, payload, g, rsv, gcn_w, gcn_b, Sp, T2p);
        hipLaunchKernelGGL(k_final_b,   dim3(1),      dim3(1024), 0, stream,
                           Sp, T2p, esn, ln_w, ln_b, fc1_w, fc1_b, fc2_w, fc2_b, out);
    } else {
        // Fallback: known-good atomic path.
        int*   deg  = (int*)ws;
        float* B    = ws + NN;
        float* S    = ws + 3 * (size_t)NN;
        float* T2   = ws + 3 * (size_t)NN + 128;
        float* degf = ws + 3 * (size_t)NN + 130;
        float* g    = ws + 4 * (size_t)NN + 130;
        const int eb = (EE + 255) / 256;
        const int nb = (NN + 255) / 256;
        hipLaunchKernelGGL(k_init,  dim3(1),    dim3(1024), 0, stream, (unsigned int*)ws, 3 * NN + 129);
        hipLaunchKernelGGL(k_deg1,  dim3(eb),   dim3(256), 0, stream, ei + EE, deg, EE);
        hipLaunchKernelGGL(k_g1,    dim3(nb),   dim3(256), 0, stream, deg, nf, degf, g, NN);
        hipLaunchKernelGGL(k_edge1, dim3(eb),   dim3(256), 0, stream, ei, ei + EE, g, B, EE);
        hipLaunchKernelGGL(k_node,  dim3(512),  dim3(256), 0, stream, nf, degf, B, gcn_w, gcn_b, S, T2, NN);
        hipLaunchKernelGGL(k_final, dim3(1),    dim3(128), 0, stream,
                           S, T2, esn, ln_w, ln_b, fc1_w, fc1_b, fc2_w, fc2_b, out);
    }
}

// Round 8
// 66.514 us; speedup vs baseline: 1.4616x; 1.4616x over previous
//
#include <hip/hip_runtime.h>
#include <math.h>

#define NN 100000
#define EE 1600000
#define HH 128
#define RR 500
#define AA 16
#define LN_EPS 1e-5f

// Bucketing: nodes -> 391 buckets of 256; payload packs (src<<8 | dst&255) in u32.
#define BSH 8
#define NPB 256
#define NB 391                   // ceil(100000/256)
#define MAXPB 4608               // mean 4096, sigma 64 -> +8 sigma
#define EPW 8192                 // edges per scatter workgroup
#define SCT 512                  // scatter threads
#define NWG_SC ((EE + EPW - 1) / EPW)   // 196
#define NZW 64                   // zpart slices (8 k-rows each, covers 500)

// WG0: zero gctr/S/T2. WGs 1..64: zpart[w][ch] = sum_k esn[k]*fc1_w[(HH+k)*HH+ch].
__global__ __launch_bounds__(256) void k_init_esn(unsigned int* __restrict__ zero_region,
                                                  const float* __restrict__ esn,
                                                  const float* __restrict__ fc1_w,
                                                  float* __restrict__ zpart) {
    const int w = blockIdx.x, t = threadIdx.x;
    if (w == 0) {
        for (int j = t; j < 512 + HH + 1; j += 256) zero_region[j] = 0u;
        return;
    }
    const int sl = w - 1;                 // 0..63
    const int k0 = sl * 8;
    const int k1 = min(k0 + 8, RR);
    if (t < HH) {
        float acc = 0.f;
        for (int k = k0; k < k1; ++k)
            acc = fmaf(esn[k], fc1_w[(size_t)(HH + k) * HH + t], acc);
        zpart[(size_t)sl * HH + t] = acc;
    }
}

// Bucket edges by dst: LDS bucket histogram -> one reserve atomic per (WG,bucket)
// -> per-edge LDS rank atomic + direct global payload write.
__global__ __launch_bounds__(SCT) void k_scatter(const int* __restrict__ src,
                                                 const int* __restrict__ dst,
                                                 unsigned int* __restrict__ gctr,
                                                 unsigned int* __restrict__ payload) {
    __shared__ unsigned int hist[512], rank[512], hbase[512];
    const int t = threadIdx.x;
    hist[t] = 0u; rank[t] = 0u; hbase[t] = 0u;
    __syncthreads();
    const int e0 = blockIdx.x * EPW;
    const int ecnt = min(EPW, EE - e0);
    const int nv = ecnt >> 2;
    const int4* d4 = reinterpret_cast<const int4*>(dst + e0);
    const int4* s4 = reinterpret_cast<const int4*>(src + e0);

    for (int k = t; k < nv; k += SCT) {
        int4 d = d4[k];
        atomicAdd(&hist[((unsigned)d.x) >> BSH], 1u);
        atomicAdd(&hist[((unsigned)d.y) >> BSH], 1u);
        atomicAdd(&hist[((unsigned)d.z) >> BSH], 1u);
        atomicAdd(&hist[((unsigned)d.w) >> BSH], 1u);
    }
    __syncthreads();

    if (t < NB && hist[t] > 0u) hbase[t] = atomicAdd(&gctr[t], hist[t]);
    __syncthreads();

    for (int k = t; k < nv; k += SCT) {
        int4 d = d4[k];
        int4 s = s4[k];
        #define EMIT(SS, DD) { \
            unsigned int dd = (unsigned)(DD), ss = (unsigned)(SS); \
            unsigned int b = dd >> BSH; \
            unsigned int r = atomicAdd(&rank[b], 1u); \
            unsigned int slot = hbase[b] + r; \
            if (slot < MAXPB) payload[(size_t)b * MAXPB + slot] = (ss << BSH) | (dd & (NPB - 1)); }
        EMIT(s.x, d.x) EMIT(s.y, d.y) EMIT(s.z, d.z) EMIT(s.w, d.w)
        #undef EMIT
    }
}

// Per bucket, 1024 threads: LDS degree histogram; write rsv = rsqrt(deg), g = rsv*f.
__global__ __launch_bounds__(1024) void k_bdeg_g(const unsigned int* __restrict__ gctr,
                                                 const unsigned int* __restrict__ payload,
                                                 const float* __restrict__ nf,
                                                 float* __restrict__ rsv, float* __restrict__ g) {
    __shared__ unsigned int hist[NPB];
    const int b = blockIdx.x, t = threadIdx.x;
    if (t < NPB) hist[t] = 0u;
    __syncthreads();
    const unsigned int cnt = min(gctr[b], (unsigned int)MAXPB);
    const unsigned int* pl = payload + (size_t)b * MAXPB;
    const uint4* pl4 = reinterpret_cast<const uint4*>(pl);
    const unsigned int nv = cnt >> 2;
    for (unsigned int k = t; k < nv; k += 1024) {
        uint4 p = pl4[k];
        atomicAdd(&hist[p.x & (NPB - 1)], 1u);
        atomicAdd(&hist[p.y & (NPB - 1)], 1u);
        atomicAdd(&hist[p.z & (NPB - 1)], 1u);
        atomicAdd(&hist[p.w & (NPB - 1)], 1u);
    }
    for (unsigned int k = (nv << 2) + t; k < cnt; k += 1024)
        atomicAdd(&hist[pl[k] & (NPB - 1)], 1u);
    __syncthreads();
    if (t < NPB) {
        int node = (b << BSH) + t;
        if (node < NN) {
            float df = 1.0f + (float)hist[t];
            float rs = rsqrtf(df);
            rsv[node] = rs;
            float2 f = *reinterpret_cast<const float2*>(&nf[2 * node]);
            float2 gv; gv.x = rs * f.x; gv.y = rs * f.y;
            *reinterpret_cast<float2*>(&g[2 * node]) = gv;
        }
    }
}

// Per bucket, 1024 threads: aggregate g[src] into x/y LDS planes, fold self-loop,
// GCN channel pass + relu; atomically accumulate S[128], T2 (memory-side, cheap).
__global__ __launch_bounds__(1024) void k_bagg_node(const unsigned int* __restrict__ gctr,
        const unsigned int* __restrict__ payload,
        const float* __restrict__ g, const float* __restrict__ rsv,
        const float* __restrict__ gcn_w, const float* __restrict__ gcn_b,
        float* __restrict__ S, float* __restrict__ T2) {
    __shared__ float agg[NPB * 2];
    __shared__ float shSf[HH];
    __shared__ float shw[16];
    const int b = blockIdx.x, t = threadIdx.x;
    if (t < NPB * 2) agg[t] = 0.f;
    if (t < HH) shSf[t] = 0.f;
    __syncthreads();
    const unsigned int cnt = min(gctr[b], (unsigned int)MAXPB);
    const unsigned int* pl = payload + (size_t)b * MAXPB;
    const uint4* pl4 = reinterpret_cast<const uint4*>(pl);
    const unsigned int nv = cnt >> 2;
    for (unsigned int k = t; k < nv; k += 1024) {
        uint4 p = pl4[k];
        #define ACC(P) { \
            unsigned int s = (P) >> BSH, dl = (P) & (NPB - 1); \
            float2 gv = *reinterpret_cast<const float2*>(&g[2 * s]); \
            atomicAdd(&agg[dl],       gv.x); \
            atomicAdd(&agg[NPB + dl], gv.y); }
        ACC(p.x) ACC(p.y) ACC(p.z) ACC(p.w)
        #undef ACC
    }
    for (unsigned int k = (nv << 2) + t; k < cnt; k += 1024) {
        unsigned int p = pl[k];
        unsigned int s = p >> BSH, dl = p & (NPB - 1);
        float2 gv = *reinterpret_cast<const float2*>(&g[2 * s]);
        atomicAdd(&agg[dl],       gv.x);
        atomicAdd(&agg[NPB + dl], gv.y);
    }
    __syncthreads();

    const int nvalid = min(NPB, NN - (b << BSH));
    if (t < nvalid) {
        int node = (b << BSH) + t;
        float rs = rsv[node];
        float2 gv = *reinterpret_cast<const float2*>(&g[2 * node]);
        agg[t]       = rs * (agg[t]       + gv.x);
        agg[NPB + t] = rs * (agg[NPB + t] + gv.y);
    }
    __syncthreads();

    const int ch = t & (HH - 1), slot = t >> 7;
    const float w0 = gcn_w[ch], w1 = gcn_w[HH + ch], bb = gcn_b[ch];
    float accS = 0.f, accT2 = 0.f;
    for (int j = slot; j < nvalid; j += 8) {
        float x = fmaf(agg[j], w0, fmaf(agg[NPB + j], w1, bb));
        float r = fmaxf(x, 0.f);
        accS  += r;
        accT2 += r * r;
    }
    atomicAdd(&shSf[ch], accS);
    float v = accT2;
    for (int o = 32; o; o >>= 1) v += __shfl_down(v, o, 64);
    if ((t & 63) == 0) shw[t >> 6] = v;
    __syncthreads();
    if (t < HH) atomicAdd(&S[t], shSf[t]);
    if (t == 0) {
        float s2 = 0.f;
        #pragma unroll
        for (int w = 0; w < 16; ++w) s2 += shw[w];
        atomicAdd(T2, s2);
    }
}

// Single block, 1024 threads: LN-collapse + fc1 (pooled half, 8-way k-split)
// + zpart sum + fc2 + log_softmax. ~25 serial memory rounds total.
__global__ __launch_bounds__(1024) void k_final2(const float* __restrict__ S,
                        const float* __restrict__ T2ptr,
                        const float* __restrict__ zpart,
                        const float* __restrict__ ln_w, const float* __restrict__ ln_b,
                        const float* __restrict__ fc1_w, const float* __restrict__ fc1_b,
                        const float* __restrict__ fc2_w, const float* __restrict__ fc2_b,
                        float* __restrict__ out) {
    const int t = threadIdx.x;
    const int ch = t & (HH - 1), sl = t >> 7;        // sl in 0..7
    __shared__ float psum[8][HH];
    __shared__ float sh_pooled[HH], sh_z[HH], sh_logits[AA];
    __shared__ float shred[2];

    // load S, reduce T1
    if (t < HH) {
        float s = S[t];
        sh_pooled[t] = s;
        float vv = s;
        for (int o = 32; o; o >>= 1) vv += __shfl_down(vv, o, 64);
        if ((t & 63) == 0) shred[t >> 6] = vv;
    }
    __syncthreads();

    const float T1 = shred[0] + shred[1];
    const float T2 = *T2ptr;
    const float cnt = (float)NN * (float)HH;
    const float mean = T1 / cnt;
    const float var  = T2 / cnt - mean * mean;
    const float denom = sqrtf(var) + LN_EPS;
    if (t < HH)
        sh_pooled[t] = ln_w[t] * (sh_pooled[t] - (float)NN * mean) / denom + (float)NN * ln_b[t];
    __syncthreads();

    // fc1 pooled half (k<HH), 8-way k-split (16 rounds) + zpart sum (8 rounds)
    float acc = 0.f;
    for (int k = sl * 16; k < sl * 16 + 16; ++k)
        acc = fmaf(sh_pooled[k], fc1_w[(size_t)k * HH + ch], acc);
    for (int w = sl * 8; w < sl * 8 + 8; ++w)
        acc += zpart[(size_t)w * HH + ch];
    psum[sl][ch] = acc;
    __syncthreads();
    if (t < HH) {
        float a = fc1_b[t];
        #pragma unroll
        for (int k = 0; k < 8; ++k) a += psum[k][t];
        sh_z[t] = fmaxf(a, 0.f);
    }
    __syncthreads();

    if (t < AA) {
        float l = fc2_b[t];
        for (int j = 0; j < HH; ++j)
            l = fmaf(sh_z[j], fc2_w[j * AA + t], l);
        sh_logits[t] = l;
    }
    __syncthreads();

    if (t == 0) {
        float m = sh_logits[0];
        for (int a = 1; a < AA; ++a) m = fmaxf(m, sh_logits[a]);
        float sum = 0.f;
        for (int a = 0; a < AA; ++a) sum += expf(sh_logits[a] - m);
        float lse = m + logf(sum);
        for (int a = 0; a < AA; ++a) out[a] = sh_logits[a] - lse;
    }
}

// ---------------- fallback path (round-2 known-good) ----------------

__global__ void k_initf(unsigned int* __restrict__ p, int n) {
    int i = blockIdx.x * blockDim.x + threadIdx.x;
    int stride = gridDim.x * blockDim.x;
    for (int j = i; j < n; j += stride) p[j] = 0u;
}

__global__ void k_deg1(const int* __restrict__ dst, int* __restrict__ deg, int e) {
    int i = blockIdx.x * blockDim.x + threadIdx.x;
    if (i < e) atomicAdd(&deg[dst[i]], 1);
}

__global__ void k_g1(const int* __restrict__ deg, const float* __restrict__ nf,
                     float* __restrict__ degf, float* __restrict__ g, int n) {
    int i = blockIdx.x * blockDim.x + threadIdx.x;
    if (i < n) {
        float df = (float)(1 + deg[i]);
        degf[i] = df;
        float rs = rsqrtf(df);
        float2 f = *reinterpret_cast<const float2*>(&nf[2 * i]);
        float2 gv; gv.x = rs * f.x; gv.y = rs * f.y;
        *reinterpret_cast<float2*>(&g[2 * i]) = gv;
    }
}

__global__ void k_edge1(const int* __restrict__ src, const int* __restrict__ dst,
                        const float* __restrict__ g, float* __restrict__ B, int e) {
    int i = blockIdx.x * blockDim.x + threadIdx.x;
    if (i < e) {
        int s = src[i], d = dst[i];
        float2 gv = *reinterpret_cast<const float2*>(&g[2 * s]);
        atomicAdd(&B[2 * d],     gv.x);
        atomicAdd(&B[2 * d + 1], gv.y);
    }
}

__global__ void k_node(const float* __restrict__ nf, const float* __restrict__ degf,
                       const float* __restrict__ B,
                       const float* __restrict__ gcn_w, const float* __restrict__ gcn_b,
                       float* __restrict__ S, float* __restrict__ T2, int n) {
    const int ch   = threadIdx.x & (HH - 1);
    const int slot = threadIdx.x >> 7;
    const float w0 = gcn_w[ch];
    const float w1 = gcn_w[HH + ch];
    const float b  = gcn_b[ch];
    float accS = 0.f, accT2 = 0.f;
    for (int i = blockIdx.x * 2 + slot; i < n; i += gridDim.x * 2) {
        float df   = degf[i];
        float invd = 1.0f / df;
        float rs   = rsqrtf(df);
        float2 bv = *reinterpret_cast<const float2*>(&B[2 * i]);
        float2 f  = *reinterpret_cast<const float2*>(&nf[2 * i]);
        float b0 = rs * bv.x + f.x * invd;
        float b1 = rs * bv.y + f.y * invd;
        float xv = fmaf(b0, w0, fmaf(b1, w1, b));
        float r  = fmaxf(xv, 0.f);
        accS  += r;
        accT2 += r * r;
    }
    __shared__ float shS[HH];
    if (slot == 1) shS[ch] = accS;
    __syncthreads();
    if (slot == 0) atomicAdd(&S[ch], accS + shS[ch]);
    float v = accT2;
    for (int o = 32; o; o >>= 1) v += __shfl_down(v, o, 64);
    __shared__ float shw[4];
    if ((threadIdx.x & 63) == 0) shw[threadIdx.x >> 6] = v;
    __syncthreads();
    if (threadIdx.x == 0) atomicAdd(T2, shw[0] + shw[1] + shw[2] + shw[3]);
}

__global__ void k_final(const float* __restrict__ S, const float* __restrict__ T2ptr,
                        const float* __restrict__ esn,
                        const float* __restrict__ ln_w, const float* __restrict__ ln_b,
                        const float* __restrict__ fc1_w, const float* __restrict__ fc1_b,
                        const float* __restrict__ fc2_w, const float* __restrict__ fc2_b,
                        float* __restrict__ out) {
    const int t = threadIdx.x;
    __shared__ float sh_pooled[HH];
    __shared__ float sh_z[HH];
    __shared__ float sh_logits[AA];
    __shared__ float shred[2];

    float s = S[t];
    float v = s;
    for (int o = 32; o; o >>= 1) v += __shfl_down(v, o, 64);
    if ((t & 63) == 0) shred[t >> 6] = v;
    __syncthreads();
    const float T1 = shred[0] + shred[1];
    const float T2 = *T2ptr;
    const float cnt = (float)NN * (float)HH;
    const float mean = T1 / cnt;
    const float var  = T2 / cnt - mean * mean;
    const float denom = sqrtf(var) + LN_EPS;
    sh_pooled[t] = ln_w[t] * (s - (float)NN * mean) / denom + (float)NN * ln_b[t];
    __syncthreads();

    float acc = fc1_b[t];
    for (int k = 0; k < HH; ++k)
        acc = fmaf(sh_pooled[k], fc1_w[k * HH + t], acc);
    for (int k = 0; k < RR; ++k)
        acc = fmaf(esn[k], fc1_w[(HH + k) * HH + t], acc);
    sh_z[t] = fmaxf(acc, 0.f);
    __syncthreads();

    if (t < AA) {
        float l = fc2_b[t];
        for (int j = 0; j < HH; ++j)
            l = fmaf(sh_z[j], fc2_w[j * AA + t], l);
        sh_logits[t] = l;
    }
    __syncthreads();

    if (t == 0) {
        float m = sh_logits[0];
        for (int a = 1; a < AA; ++a) m = fmaxf(m, sh_logits[a]);
        float sum = 0.f;
        for (int a = 0; a < AA; ++a) sum += expf(sh_logits[a] - m);
        float lse = m + logf(sum);
        for (int a = 0; a < AA; ++a) out[a] = sh_logits[a] - lse;
    }
}

extern "C" void kernel_launch(void* const* d_in, const int* in_sizes, int n_in,
                              void* d_out, int out_size, void* d_ws, size_t ws_size,
                              hipStream_t stream) {
    const float* nf     = (const float*)d_in[0];
    const int*   ei     = (const int*)d_in[1];
    const float* esn    = (const float*)d_in[2];
    const float* gcn_w  = (const float*)d_in[3];
    const float* gcn_b  = (const float*)d_in[4];
    const float* ln_w   = (const float*)d_in[5];
    const float* ln_b   = (const float*)d_in[6];
    const float* fc1_w  = (const float*)d_in[7];
    const float* fc1_b  = (const float*)d_in[8];
    const float* fc2_w  = (const float*)d_in[9];
    const float* fc2_b  = (const float*)d_in[10];
    float* out = (float*)d_out;
    float* ws  = (float*)d_ws;

    // Bucket-path layout (word offsets):
    //   gctr:0(512) | S:512(128) | T2:640(1) | zpart:644(64*128) | payload | rsv | g
    const size_t OFF_S       = 512;
    const size_t OFF_T2      = OFF_S + HH;                          // 640
    const size_t OFF_ZPART   = ((OFF_T2 + 1 + 3) & ~(size_t)3);     // 644
    const size_t OFF_PAYLOAD = OFF_ZPART + (size_t)NZW * HH;        // 8836 -> 16B-aligned (mult of 4)
    const size_t OFF_RSV     = OFF_PAYLOAD + (size_t)NB * MAXPB;
    const size_t OFF_G       = OFF_RSV + NN;                        // even -> float2 ok
    const size_t NEED_BKT    = (OFF_G + 2 * (size_t)NN) * 4;

    if (ws_size >= NEED_BKT) {
        unsigned int* gctr    = (unsigned int*)ws;
        float*        S       = ws + OFF_S;
        float*        T2      = ws + OFF_T2;
        float*        zpart   = ws + OFF_ZPART;
        unsigned int* payload = (unsigned int*)ws + OFF_PAYLOAD;
        float*        rsv     = ws + OFF_RSV;
        float*        g       = ws + OFF_G;

        hipLaunchKernelGGL(k_init_esn,  dim3(NZW + 1), dim3(256),  0, stream, (unsigned int*)ws, esn, fc1_w, zpart);
        hipLaunchKernelGGL(k_scatter,   dim3(NWG_SC),  dim3(SCT),  0, stream, ei, ei + EE, gctr, payload);
        hipLaunchKernelGGL(k_bdeg_g,    dim3(NB),      dim3(1024), 0, stream, gctr, payload, nf, rsv, g);
        hipLaunchKernelGGL(k_bagg_node, dim3(NB),      dim3(1024), 0, stream, gctr, payload, g, rsv, gcn_w, gcn_b, S, T2);
        hipLaunchKernelGGL(k_final2,    dim3(1),       dim3(1024), 0, stream,
                           S, T2, zpart, ln_w, ln_b, fc1_w, fc1_b, fc2_w, fc2_b, out);
    } else {
        // Fallback: known-good atomic path.
        int*   deg  = (int*)ws;
        float* B    = ws + NN;
        float* S    = ws + 3 * (size_t)NN;
        float* T2   = ws + 3 * (size_t)NN + 128;
        float* degf = ws + 3 * (size_t)NN + 130;
        float* g    = ws + 4 * (size_t)NN + 130;
        const int eb = (EE + 255) / 256;
        const int nb = (NN + 255) / 256;
        hipLaunchKernelGGL(k_initf, dim3(2048), dim3(256), 0, stream, (unsigned int*)ws, 3 * NN + 129);
        hipLaunchKernelGGL(k_deg1,  dim3(eb),   dim3(256), 0, stream, ei + EE, deg, EE);
        hipLaunchKernelGGL(k_g1,    dim3(nb),   dim3(256), 0, stream, deg, nf, degf, g, NN);
        hipLaunchKernelGGL(k_edge1, dim3(eb),   dim3(256), 0, stream, ei, ei + EE, g, B, EE);
        hipLaunchKernelGGL(k_node,  dim3(512),  dim3(256), 0, stream, nf, degf, B, gcn_w, gcn_b, S, T2, NN);
        hipLaunchKernelGGL(k_final, dim3(1),    dim3(128), 0, stream,
                           S, T2, esn, ln_w, ln_b, fc1_w, fc1_b, fc2_w, fc2_b, out);
    }
}